// Round 1
// baseline (1917.010 us; speedup 1.0000x reference)
//
#include <hip/hip_runtime.h>

// Problem constants (fixed by setup_inputs)
constexpr int B = 4, C = 3, H = 1080, W = 1920;
constexpr int HW = H * W;
constexpr int N = B * HW;                 // 8,294,400 source pixels
constexpr float MOTION_TH = 25.0f;        // 0.25 * 100
constexpr float EPS = 1e-5f;

// ---------------------------------------------------------------------------
// Phase 1: scatter-max depth into dbuf[N]
// ---------------------------------------------------------------------------
__global__ void depth_pass(const float* __restrict__ flow, int* __restrict__ dbuf) {
    int n = blockIdx.x * blockDim.x + threadIdx.x;
    if (n >= N) return;
    int b   = n / HW;
    int pix = n - b * HW;
    int y   = pix / W;
    int x   = pix - y * W;

    float fx = flow[2 * n];
    float fy = flow[2 * n + 1];
    float xd = (float)x + fx;
    float yd = (float)y + fy;

    float xf = floorf(xd), yf = floorf(yd);
    int xfi = (int)xf, yfi = (int)yf;
    int xci = xfi + 1, yci = yfi + 1;
    bool valid = (xfi >= 0) & (xci <= W) & (yfi >= 0) & (yci <= H);
    if (!valid) return;

    int di = (int)(100.0f * sqrtf(fx * fx + fy * fy));

    float wx1 = xd - xf;            // x_dest - xf_f
    float wx0 = (xf + 1.0f) - xd;   // xc_f - x_dest
    float wy1 = yd - yf;
    float wy0 = (yf + 1.0f) - yd;

    int x0 = min(max(xfi, 0), W - 1), x1 = min(max(xci, 0), W - 1);
    int y0 = min(max(yfi, 0), H - 1), y1 = min(max(yci, 0), H - 1);
    int base = b * HW;

    float k;
    k = wx0 * wy0; if (k >= 0.25f) atomicMax(&dbuf[base + y0 * W + x0], di);
    k = wx1 * wy0; if (k >= 0.25f) atomicMax(&dbuf[base + y0 * W + x1], di);
    k = wx0 * wy1; if (k >= 0.25f) atomicMax(&dbuf[base + y1 * W + x0], di);
    k = wx1 * wy1; if (k >= 0.25f) atomicMax(&dbuf[base + y1 * W + x1], di);
}

// ---------------------------------------------------------------------------
// Phase 2: z-tested bilinear splat of im0 into out (channel sums) + wbuf
// ---------------------------------------------------------------------------
__global__ void splat_pass(const float* __restrict__ im0,
                           const float* __restrict__ flow,
                           const int* __restrict__ dbuf,
                           float* __restrict__ out,
                           float* __restrict__ wbuf) {
    int n = blockIdx.x * blockDim.x + threadIdx.x;
    if (n >= N) return;
    int b   = n / HW;
    int pix = n - b * HW;
    int y   = pix / W;
    int x   = pix - y * W;

    float fx = flow[2 * n];
    float fy = flow[2 * n + 1];
    float xd = (float)x + fx;
    float yd = (float)y + fy;

    float xf = floorf(xd), yf = floorf(yd);
    int xfi = (int)xf, yfi = (int)yf;
    int xci = xfi + 1, yci = yfi + 1;
    bool valid = (xfi >= 0) & (xci <= W) & (yfi >= 0) & (yci <= H);
    if (!valid) return;

    int di = (int)(100.0f * sqrtf(fx * fx + fy * fy));
    float df = (float)di;

    float wx1 = xd - xf;
    float wx0 = (xf + 1.0f) - xd;
    float wy1 = yd - yf;
    float wy0 = (yf + 1.0f) - yd;

    int x0 = min(max(xfi, 0), W - 1), x1 = min(max(xci, 0), W - 1);
    int y0 = min(max(yfi, 0), H - 1), y1 = min(max(yci, 0), H - 1);
    int base = b * HW;

    // source pixel values (coalesced reads)
    float v0 = im0[(b * C + 0) * HW + pix];
    float v1 = im0[(b * C + 1) * HW + pix];
    float v2 = im0[(b * C + 2) * HW + pix];

    int outBatch = b * C * HW;

    int   cx[4] = { x0, x1, x0, x1 };
    int   cy[4] = { y0, y0, y1, y1 };
    float ck[4] = { wx0 * wy0, wx1 * wy0, wx0 * wy1, wx1 * wy1 };

    #pragma unroll
    for (int c = 0; c < 4; ++c) {
        float k = ck[c];
        if (k < 0.25f) continue;
        int p   = cy[c] * W + cx[c];
        int idx = base + p;
        float dg = (float)dbuf[idx];
        if (dg - df <= MOTION_TH) {
            atomicAdd(&wbuf[idx], k);
            int ob = outBatch + p;
            atomicAdd(&out[ob],          v0 * k);
            atomicAdd(&out[ob + HW],     v1 * k);
            atomicAdd(&out[ob + 2 * HW], v2 * k);
        }
    }
}

// ---------------------------------------------------------------------------
// Phase 3: out /= max(wbuf/C, eps)
// ---------------------------------------------------------------------------
__global__ void norm_pass(float* __restrict__ out, const float* __restrict__ wbuf) {
    int n = blockIdx.x * blockDim.x + threadIdx.x;
    if (n >= N) return;
    int b   = n / HW;
    int pix = n - b * HW;
    float g = fmaxf(wbuf[n] / 3.0f, EPS);
    float inv = 1.0f / g;
    float* p = out + b * C * HW + pix;
    p[0]      *= inv;
    p[HW]     *= inv;
    p[2 * HW] *= inv;
}

extern "C" void kernel_launch(void* const* d_in, const int* in_sizes, int n_in,
                              void* d_out, int out_size, void* d_ws, size_t ws_size,
                              hipStream_t stream) {
    const float* im0  = (const float*)d_in[0];
    const float* flow = (const float*)d_in[1];
    float* out = (float*)d_out;

    int*   dbuf = (int*)d_ws;                                   // N ints
    float* wbuf = (float*)((char*)d_ws + (size_t)N * sizeof(int)); // N floats

    // zero accumulators (graph-capturable stream memsets)
    hipMemsetAsync(d_ws, 0, (size_t)N * (sizeof(int) + sizeof(float)), stream);
    hipMemsetAsync(d_out, 0, (size_t)out_size * sizeof(float), stream);

    const int block = 256;
    const int grid  = (N + block - 1) / block;

    depth_pass<<<grid, block, 0, stream>>>(flow, dbuf);
    splat_pass<<<grid, block, 0, stream>>>(im0, flow, dbuf, out, wbuf);
    norm_pass <<<grid, block, 0, stream>>>(out, wbuf);
}